// Round 1
// baseline (31533.078 us; speedup 1.0000x reference)
//
#include <hip/hip_runtime.h>
#include <stdint.h>

static constexpr int Vv = 32000, Dd = 512, Ss = 2048, Bx = 2, Lx = 6, Hx = 8, Fx = 2048;
static constexpr int Mx = Bx * Ss;   // 4096 token rows
static constexpr int DhX = 64;

typedef __bf16 bf16x8 __attribute__((ext_vector_type(8)));
typedef float f32x4 __attribute__((ext_vector_type(4)));

__device__ __forceinline__ unsigned short f2bf(float f) {
  union { float f; unsigned u; } v; v.f = f;
  unsigned r = v.u + 0x7FFFu + ((v.u >> 16) & 1u);   // RNE
  return (unsigned short)(r >> 16);
}

__device__ __forceinline__ void async_load16(const void* g, void* l) {
  __builtin_amdgcn_global_load_lds((__attribute__((address_space(1))) void*)g,
                                   (__attribute__((address_space(3))) void*)l, 16, 0, 0);
}

// ---------------- transpose + fp32->bf16 convert: out[c][r] = in[r][c] ----------------
__global__ void transpose_kernel(const float* in, unsigned short* out,
                                 int R, int C, long inL, long outL) {
  __shared__ float t[32][33];
  const float* inp = in + (size_t)blockIdx.z * inL;
  unsigned short* outp = out + (size_t)blockIdx.z * outL;
  int c0 = blockIdx.x * 32, r0 = blockIdx.y * 32;
  for (int i = threadIdx.y; i < 32; i += 8)
    t[i][threadIdx.x] = inp[(size_t)(r0 + i) * C + c0 + threadIdx.x];
  __syncthreads();
  for (int i = threadIdx.y; i < 32; i += 8)
    outp[(size_t)(c0 + i) * R + r0 + threadIdx.x] = f2bf(t[threadIdx.x][i]);
}

// ---------------- embedding + positional encoding ----------------
__global__ void embed_kernel(const int* x, const float* emb, const float* pe,
                             float* h, unsigned short* h_bf) {
  int idx = blockIdx.x * 256 + threadIdx.x;           // < Mx*Dd
  int row = idx >> 9, d = idx & 511;
  int s = row & (Ss - 1);
  float v = emb[(size_t)x[row] * Dd + d] + pe[(size_t)s * Dd + d];
  h[idx] = v;
  h_bf[idx] = f2bf(v);
}

// ---------------- bf16 MFMA GEMM: C[M,N] = A[M,K] @ Bt[N,K]^T (+bias, +relu) ----------
// 128x128 tile, BK=32, 256 threads (4 waves in 2x2), global_load_lds width=16 staging.
__global__ __launch_bounds__(256) void gemm_kernel(
    const unsigned short* __restrict__ A, const unsigned short* __restrict__ Bt,
    const float* __restrict__ bias, float* outF, unsigned short* outB,
    int M, int N, int K, int relu)
{
  __shared__ __align__(16) unsigned short As[128 * 32];
  __shared__ __align__(16) unsigned short Bs[128 * 32];
  const int tid = threadIdx.x;
  const int lane = tid & 63, w = tid >> 6;
  const int quad = lane >> 4, r16 = lane & 15;
  const int m0 = blockIdx.y * 128, n0 = blockIdx.x * 128;
  const int wm = (w >> 1) * 64, wn = (w & 1) * 64;

  f32x4 acc[4][4] = {};

  const int nchunk = K >> 5;
  const int c0 = tid, c1 = tid + 256;   // 16B chunk ids: chunk c covers row c/4, cols (c%4)*8..+7
  for (int kk = 0; kk < nchunk; ++kk) {
    const int k0 = kk << 5;
    __syncthreads();   // previous compute done before LDS overwrite
    async_load16(A  + ((size_t)(m0 + (c0 >> 2)) * K + k0 + (c0 & 3) * 8), As + (size_t)(w * 64) * 8);
    async_load16(A  + ((size_t)(m0 + (c1 >> 2)) * K + k0 + (c1 & 3) * 8), As + (size_t)(256 + w * 64) * 8);
    async_load16(Bt + ((size_t)(n0 + (c0 >> 2)) * K + k0 + (c0 & 3) * 8), Bs + (size_t)(w * 64) * 8);
    async_load16(Bt + ((size_t)(n0 + (c1 >> 2)) * K + k0 + (c1 & 3) * 8), Bs + (size_t)(256 + w * 64) * 8);
    __syncthreads();   // compiler drains vmcnt before s_barrier
    bf16x8 af[4], bfr[4];
    #pragma unroll
    for (int i = 0; i < 4; ++i)
      af[i] = *(const bf16x8*)(As + ((wm + i * 16 + r16) * 32 + quad * 8));
    #pragma unroll
    for (int j = 0; j < 4; ++j)
      bfr[j] = *(const bf16x8*)(Bs + ((wn + j * 16 + r16) * 32 + quad * 8));
    #pragma unroll
    for (int i = 0; i < 4; ++i)
      #pragma unroll
      for (int j = 0; j < 4; ++j)
        acc[i][j] = __builtin_amdgcn_mfma_f32_16x16x32_bf16(af[i], bfr[j], acc[i][j], 0, 0, 0);
  }

  #pragma unroll
  for (int j = 0; j < 4; ++j) {
    const int col = n0 + wn + j * 16 + r16;
    const float bv = bias ? bias[col] : 0.0f;
    #pragma unroll
    for (int i = 0; i < 4; ++i) {
      #pragma unroll
      for (int r = 0; r < 4; ++r) {
        const int row = m0 + wm + i * 16 + quad * 4 + r;
        float v = acc[i][j][r] + bv;
        if (relu) v = fmaxf(v, 0.0f);
        if (outF) outF[(size_t)row * N + col] = v;
        if (outB) outB[(size_t)row * N + col] = f2bf(v);
      }
    }
  }
}

// ---------------- K transpose: kt[bh][d][s] = qkv[b,s, D + h*64 + d] ----------------
__global__ void kt_kernel(const float* qkv, float* kt) {
  __shared__ float t[32][33];
  const int bh = blockIdx.z, b = bh >> 3, hh = bh & 7;
  const int s0 = blockIdx.x * 32, d0 = blockIdx.y * 32;
  for (int i = threadIdx.y; i < 32; i += 8)
    t[i][threadIdx.x] = qkv[(size_t)(b * Ss + s0 + i) * (3 * Dd) + Dd + hh * 64 + d0 + threadIdx.x];
  __syncthreads();
  for (int i = threadIdx.y; i < 32; i += 8)
    kt[((size_t)bh * 64 + d0 + i) * Ss + s0 + threadIdx.x] = t[threadIdx.x][i];
}

// ---------------- causal attention, fp32, one workgroup per (b,h,q) row -------------
__global__ __launch_bounds__(256) void attn_kernel(const float* __restrict__ qkv,
                                                   const float* __restrict__ kt,
                                                   unsigned short* __restrict__ attn_bf) {
  const int q = blockIdx.x & (Ss - 1);
  const int bh = blockIdx.x >> 11;       // S = 2048
  const int b = bh >> 3, hh = bh & 7;
  const int tid = threadIdx.x;
  __shared__ float qv[64];
  __shared__ float sc[Ss];
  __shared__ float red[256];
  if (tid < 64) qv[tid] = qkv[(size_t)(b * Ss + q) * (3 * Dd) + hh * 64 + tid];
  __syncthreads();
  const int nk = q + 1;
  const float* ktb = kt + (size_t)bh * 64 * Ss;
  float lmax = -1e30f;
  const int nc = (nk + 3) >> 2;
  for (int c = tid; c < nc; c += 256) {
    const float* kp = ktb + c * 4;
    float ax = 0, ay = 0, az = 0, aw = 0;
    #pragma unroll
    for (int d = 0; d < 64; ++d) {
      float4 kv = *(const float4*)(kp + (size_t)d * Ss);
      float qd = qv[d];
      ax += kv.x * qd; ay += kv.y * qd; az += kv.z * qd; aw += kv.w * qd;
    }
    const int k = c * 4;
    ax *= 0.125f; ay *= 0.125f; az *= 0.125f; aw *= 0.125f;
    if (k + 3 < nk) {
      *(float4*)(sc + k) = make_float4(ax, ay, az, aw);
      lmax = fmaxf(lmax, fmaxf(fmaxf(ax, ay), fmaxf(az, aw)));
    } else {
      if (k     < nk) { sc[k]     = ax; lmax = fmaxf(lmax, ax); }
      if (k + 1 < nk) { sc[k + 1] = ay; lmax = fmaxf(lmax, ay); }
      if (k + 2 < nk) { sc[k + 2] = az; lmax = fmaxf(lmax, az); }
    }
  }
  red[tid] = lmax; __syncthreads();
  for (int off = 128; off > 0; off >>= 1) {
    if (tid < off) red[tid] = fmaxf(red[tid], red[tid + off]);
    __syncthreads();
  }
  const float mmax = red[0];
  __syncthreads();
  float lsum = 0.f;
  for (int k = tid; k < nk; k += 256) {
    float p = __expf(sc[k] - mmax);
    sc[k] = p; lsum += p;
  }
  red[tid] = lsum; __syncthreads();
  for (int off = 128; off > 0; off >>= 1) {
    if (tid < off) red[tid] += red[tid + off];
    __syncthreads();
  }
  const float inv = 1.0f / red[0];
  __syncthreads();
  const int g = tid >> 6, d = tid & 63;
  const float* vb = qkv + (size_t)b * Ss * (3 * Dd) + 2 * Dd + hh * 64 + d;
  float acc = 0.f;
  for (int k = g; k < nk; k += 4) acc += sc[k] * vb[(size_t)k * (3 * Dd)];
  red[tid] = acc; __syncthreads();
  if (tid < 64) {
    float o = (red[d] + red[64 + d] + red[128 + d] + red[192 + d]) * inv;
    attn_bf[(size_t)(b * Ss + q) * Dd + hh * 64 + d] = f2bf(o);
  }
}

// ---------------- LayerNorm (+optional residual add), fp32 + bf16 outputs ------------
__global__ __launch_bounds__(256) void ln_kernel(const float* x, const float* res,
                                                 const float* g, const float* b,
                                                 float* outF, unsigned short* outB) {
  const int row = blockIdx.x, tid = threadIdx.x;
  const size_t base = (size_t)row * Dd;
  float v0 = x[base + tid], v1 = x[base + tid + 256];
  if (res) { v0 += res[base + tid]; v1 += res[base + tid + 256]; }
  __shared__ float s1[256], s2[256];
  s1[tid] = v0 + v1; s2[tid] = v0 * v0 + v1 * v1;
  __syncthreads();
  for (int off = 128; off > 0; off >>= 1) {
    if (tid < off) { s1[tid] += s1[tid + off]; s2[tid] += s2[tid + off]; }
    __syncthreads();
  }
  const float mean = s1[0] * (1.0f / Dd);
  const float var  = s2[0] * (1.0f / Dd) - mean * mean;
  const float rstd = rsqrtf(var + 1e-5f);
  const float o0 = (v0 - mean) * rstd * g[tid] + b[tid];
  const float o1 = (v1 - mean) * rstd * g[tid + 256] + b[tid + 256];
  if (outF) { outF[base + tid] = o0; outF[base + tid + 256] = o1; }
  if (outB) { outB[base + tid] = f2bf(o0); outB[base + tid + 256] = f2bf(o1); }
}

// =====================================================================================
extern "C" void kernel_launch(void* const* d_in, const int* in_sizes, int n_in,
                              void* d_out, int out_size, void* d_ws, size_t ws_size,
                              hipStream_t stream) {
  const int*   x    = (const int*)d_in[0];
  const float* emb  = (const float*)d_in[1];
  const float* pe   = (const float*)d_in[2];
  const float* Wqkv = (const float*)d_in[3];
  const float* Wo   = (const float*)d_in[4];
  const float* bo   = (const float*)d_in[5];
  const float* g1   = (const float*)d_in[6];
  const float* b1   = (const float*)d_in[7];
  const float* g2   = (const float*)d_in[8];
  const float* b2   = (const float*)d_in[9];
  const float* W1   = (const float*)d_in[10];
  const float* bf1  = (const float*)d_in[11];
  const float* W2   = (const float*)d_in[12];
  const float* bf2  = (const float*)d_in[13];
  const float* gfin = (const float*)d_in[14];
  const float* bfin = (const float*)d_in[15];
  const float* Wout = (const float*)d_in[16];
  const float* bfc  = (const float*)d_in[17];
  float* out = (float*)d_out;
  (void)in_sizes; (void)n_in; (void)out_size; (void)ws_size;

  char* wsp = (char*)d_ws;
  size_t off = 0;
  auto take = [&](size_t bytes) -> void* {
    void* p = wsp + off;
    off += (bytes + 255) & ~(size_t)255;
    return p;
  };
  unsigned short* WqkvT  = (unsigned short*)take((size_t)Lx * 3 * Dd * Dd * 2);
  unsigned short* WoT    = (unsigned short*)take((size_t)Lx * Dd * Dd * 2);
  unsigned short* W1T    = (unsigned short*)take((size_t)Lx * Fx * Dd * 2);
  unsigned short* W2T    = (unsigned short*)take((size_t)Lx * Dd * Fx * 2);
  unsigned short* WoutT  = (unsigned short*)take((size_t)Vv * Dd * 2);
  float*          h      = (float*)take((size_t)Mx * Dd * 4);
  unsigned short* h_bf   = (unsigned short*)take((size_t)Mx * Dd * 2);
  float*          qkv    = (float*)take((size_t)Mx * 3 * Dd * 4);
  float*          kt     = (float*)take((size_t)Bx * Hx * DhX * Ss * 4 + 256);
  unsigned short* attnbf = (unsigned short*)take((size_t)Mx * Dd * 2);
  float*          obuf   = (float*)take((size_t)Mx * Dd * 4);
  unsigned short* ff1bf  = (unsigned short*)take((size_t)Mx * Fx * 2);
  unsigned short* hfbf   = (unsigned short*)take((size_t)Mx * Dd * 2);

  dim3 tb(32, 8);
  // weight convert+transpose to bf16 [N,K]
  transpose_kernel<<<dim3(3 * Dd / 32, Dd / 32, Lx), tb, 0, stream>>>(Wqkv, WqkvT, Dd, 3 * Dd, (long)Dd * 3 * Dd, (long)3 * Dd * Dd);
  transpose_kernel<<<dim3(Dd / 32, Dd / 32, Lx), tb, 0, stream>>>(Wo, WoT, Dd, Dd, (long)Dd * Dd, (long)Dd * Dd);
  transpose_kernel<<<dim3(Fx / 32, Dd / 32, Lx), tb, 0, stream>>>(W1, W1T, Dd, Fx, (long)Dd * Fx, (long)Fx * Dd);
  transpose_kernel<<<dim3(Dd / 32, Fx / 32, Lx), tb, 0, stream>>>(W2, W2T, Fx, Dd, (long)Fx * Dd, (long)Dd * Fx);
  transpose_kernel<<<dim3(Vv / 32, Dd / 32, 1), tb, 0, stream>>>(Wout, WoutT, Dd, Vv, 0, 0);

  embed_kernel<<<Mx * Dd / 256, 256, 0, stream>>>(x, emb, pe, h, h_bf);

  for (int l = 0; l < Lx; ++l) {
    gemm_kernel<<<dim3(3 * Dd / 128, Mx / 128), 256, 0, stream>>>(h_bf, WqkvT + (size_t)l * 3 * Dd * Dd, nullptr, qkv, nullptr, Mx, 3 * Dd, Dd, 0);
    kt_kernel<<<dim3(Ss / 32, DhX / 32, Bx * Hx), tb, 0, stream>>>(qkv, kt);
    attn_kernel<<<Bx * Hx * Ss, 256, 0, stream>>>(qkv, kt, attnbf);
    gemm_kernel<<<dim3(Dd / 128, Mx / 128), 256, 0, stream>>>(attnbf, WoT + (size_t)l * Dd * Dd, bo + (size_t)l * Dd, obuf, nullptr, Mx, Dd, Dd, 0);
    ln_kernel<<<Mx, 256, 0, stream>>>(h, obuf, g1 + (size_t)l * Dd, b1 + (size_t)l * Dd, h, h_bf);
    gemm_kernel<<<dim3(Fx / 128, Mx / 128), 256, 0, stream>>>(h_bf, W1T + (size_t)l * Fx * Dd, bf1 + (size_t)l * Fx, nullptr, ff1bf, Mx, Fx, Dd, 1);
    gemm_kernel<<<dim3(Dd / 128, Mx / 128), 256, 0, stream>>>(ff1bf, W2T + (size_t)l * Dd * Fx, bf2 + (size_t)l * Dd, obuf, nullptr, Mx, Dd, Fx, 0);
    ln_kernel<<<Mx, 256, 0, stream>>>(h, obuf, g2 + (size_t)l * Dd, b2 + (size_t)l * Dd, h, h_bf);
  }
  ln_kernel<<<Mx, 256, 0, stream>>>(h, nullptr, gfin, bfin, nullptr, hfbf);
  gemm_kernel<<<dim3(Vv / 128, Mx / 128), 256, 0, stream>>>(hfbf, WoutT, bfc, out, nullptr, Mx, Vv, Dd, 0);
}